// Round 11
// baseline (169.418 us; speedup 1.0000x reference)
//
#include <hip/hip_runtime.h>
#include <type_traits>

typedef __bf16 bf16;
typedef __bf16 bf16x8 __attribute__((ext_vector_type(8)));
typedef __bf16 bf16x4 __attribute__((ext_vector_type(4)));
typedef float floatx4 __attribute__((ext_vector_type(4)));
typedef float floatx16 __attribute__((ext_vector_type(16)));

#define SEQ 4096
#define DM 1024
#define NH 16
#define HD 64
#define GUARD 64

__device__ __forceinline__ floatx4 mfma32(bf16x8 a, bf16x8 b, floatx4 c) {
    return __builtin_amdgcn_mfma_f32_16x16x32_bf16(a, b, c, 0, 0, 0);
}
__device__ __forceinline__ floatx16 mfma3216(bf16x8 a, bf16x8 b, floatx16 c) {
    return __builtin_amdgcn_mfma_f32_32x32x16_bf16(a, b, c, 0, 0, 0);
}

__device__ __forceinline__ bf16x8 load8(const bf16* p) {
    return *(const bf16x8*)p;
}

__device__ __forceinline__ void async_ld16(const bf16* g, bf16* l) {
    __builtin_amdgcn_global_load_lds(
        (const __attribute__((address_space(1))) unsigned int*)g,
        (__attribute__((address_space(3))) unsigned int*)l,
        16, 0, 0);
}

// fused prep: cast x, Wq,Wk,Wv,Wo to bf16; concat biases to fp32 bcat.
__global__ __launch_bounds__(256) void prep_kernel(
    const float* __restrict__ x,  const float* __restrict__ Wq,
    const float* __restrict__ Wk, const float* __restrict__ Wv,
    const float* __restrict__ Wo, const float* __restrict__ bq,
    const float* __restrict__ bk, const float* __restrict__ bv,
    bf16* __restrict__ xb, bf16* __restrict__ Wcat,
    bf16* __restrict__ Wob, float* __restrict__ bcat)
{
    const int WN8 = 131072;           // (1024*1024)/8
    const int XN8 = 524288;           // (4096*1024)/8
    int b = blockIdx.x;
    if (b == 4096) {
        for (int k = threadIdx.x; k < 3 * DM; k += 256)
            bcat[k] = k < DM ? bq[k] : (k < 2 * DM ? bk[k - DM] : bv[k - 2 * DM]);
        return;
    }
    int c = b * 256 + threadIdx.x;
    const float* src; bf16* dst;
    if (c < XN8)              { src = x;  dst = xb; }
    else if (c < XN8 + WN8)   { src = Wq; dst = Wcat;                 c -= XN8; }
    else if (c < XN8 + 2*WN8) { src = Wk; dst = Wcat + (size_t)DM*DM;     c -= XN8 + WN8; }
    else if (c < XN8 + 3*WN8) { src = Wv; dst = Wcat + (size_t)2*DM*DM;   c -= XN8 + 2*WN8; }
    else                      { src = Wo; dst = Wob;                  c -= XN8 + 3*WN8; }
    float4 a = ((const float4*)src)[2 * c], d2 = ((const float4*)src)[2 * c + 1];
    bf16x8 o;
    o[0] = (bf16)a.x;  o[1] = (bf16)a.y;  o[2] = (bf16)a.z;  o[3] = (bf16)a.w;
    o[4] = (bf16)d2.x; o[5] = (bf16)d2.y; o[6] = (bf16)d2.z; o[7] = (bf16)d2.w;
    *(bf16x8*)(dst + 8 * (size_t)c) = o;
}

// ---- QKV projection GEMM: [4096,1024] @ [3072,1024]^T, head-major outputs.
// BM=128, BN=128, BK=64, XOR-swizzled LDS staging (0 conflicts, r6).
// r11: 32x32x16 MFMA (2382 vs 2075 TF ceiling; half the MFMA instructions
// for the same 16 ds_read_b128 per BK). C/D: col=lane&31,
// row=(reg&3)+8*(reg>>2)+4*(lane>>5) -> 4-consecutive-col groups, packed st.
__global__ __launch_bounds__(256, 3) void gemm_qkv_kernel(
    const bf16* __restrict__ A,      // xb [4096][1024]
    const bf16* __restrict__ B,      // Wcat [3072][1024]
    const float* __restrict__ bias,  // bcat [3072]
    bf16* __restrict__ Qh, bf16* __restrict__ Kh, bf16* __restrict__ Vt)
{
    constexpr int K = DM;
    __shared__ bf16 As[128 * 64];
    __shared__ bf16 Bs[128 * 64];

    const int tid  = threadIdx.x;
    const int wave = tid >> 6;
    const int lane = tid & 63;
    const int l31  = lane & 31;
    const int lhalf = lane >> 5;
    const int m0 = blockIdx.x * 128;
    const int n0 = blockIdx.y * 128;
    const int wm = (wave & 1) * 64;
    const int wn = (wave >> 1) * 64;

    // staging: chunk = 8 rows x 64 cols (1024B). lane -> (row lane>>3,
    // LDS slot lane&7); global col chunk gc = (slot - row)&7  [XOR swizzle]
    const int lr = lane >> 3;
    const int gc = ((lane & 7) - lr) & 7;

    const bf16* aptr[4]; bf16* alds[4];
    const bf16* bptr[4]; bf16* blds[4];
#pragma unroll
    for (int i = 0; i < 4; ++i) {
        int ci = wave + 4 * i;
        aptr[i] = A + (size_t)(m0 + ci * 8 + lr) * K + gc * 8;
        alds[i] = As + ci * 512;
        bptr[i] = B + (size_t)(n0 + ci * 8 + lr) * K + gc * 8;
        blds[i] = Bs + ci * 512;
    }

    floatx16 acc[2][2] = {};   // SW: [ni][mi]; non-SW: [mi][ni]
    const bool qk = (n0 < 2 * DM);
    const int sl7 = l31 & 7;   // row&7 component of the read swizzle

    auto kloop = [&](auto swtag) {
        constexpr bool SW = decltype(swtag)::value;
        for (int k0 = 0; k0 < K; k0 += 64) {
            __syncthreads();
#pragma unroll
            for (int i = 0; i < 4; ++i) async_ld16(aptr[i] + k0, alds[i]);
#pragma unroll
            for (int i = 0; i < 4; ++i) async_ld16(bptr[i] + k0, blds[i]);
            __syncthreads();
#pragma unroll
            for (int kc = 0; kc < 4; ++kc) {
                const int g = kc * 2 + lhalf;            // global 8-col chunk
                const int so = ((g + sl7) & 7) * 8;      // swizzled slot
                bf16x8 af[2], bfr[2];
#pragma unroll
                for (int mi = 0; mi < 2; ++mi)
                    af[mi] = load8(As + (wm + mi * 32 + l31) * 64 + so);
#pragma unroll
                for (int ni = 0; ni < 2; ++ni)
                    bfr[ni] = load8(Bs + (wn + ni * 32 + l31) * 64 + so);
                if constexpr (SW) {
#pragma unroll
                    for (int ni = 0; ni < 2; ++ni)
#pragma unroll
                        for (int mi = 0; mi < 2; ++mi)
                            acc[ni][mi] = mfma3216(bfr[ni], af[mi], acc[ni][mi]);
                } else {
#pragma unroll
                    for (int mi = 0; mi < 2; ++mi)
#pragma unroll
                        for (int ni = 0; ni < 2; ++ni)
                            acc[mi][ni] = mfma3216(af[mi], bfr[ni], acc[mi][ni]);
                }
            }
        }
    };
    if (qk) kloop(std::true_type{}); else kloop(std::false_type{});

    const int nb = n0 + wn;   // multiple of 64 -> exactly one head for Q/K
    if (qk) {
        // SW: D col = x-row s, D rows = out-cols d. Lane holds 4 groups of
        // 4 consecutive d: d = ni*32 + rg*8 + 4*lhalf + c.
        bf16* dst = (nb < DM) ? Qh : Kh;
        const int hh = ((nb < DM) ? nb : nb - DM) >> 6;
#pragma unroll
        for (int mi = 0; mi < 2; ++mi) {
            int s = m0 + wm + mi * 32 + l31;
            bf16* row = dst + ((size_t)hh * SEQ + s) * 64;
#pragma unroll
            for (int ni = 0; ni < 2; ++ni) {
#pragma unroll
                for (int rg = 0; rg < 4; ++rg) {
                    int d4 = ni * 32 + rg * 8 + lhalf * 4;
                    float4 bv = *(const float4*)(bias + nb + d4);
                    bf16x4 o = {(bf16)(acc[ni][mi][rg * 4 + 0] + bv.x),
                                (bf16)(acc[ni][mi][rg * 4 + 1] + bv.y),
                                (bf16)(acc[ni][mi][rg * 4 + 2] + bv.z),
                                (bf16)(acc[ni][mi][rg * 4 + 3] + bv.w)};
                    *(bf16x4*)(row + d4) = o;
                }
            }
        }
    } else {
        // non-SW: D col = out-col (V^T row), D rows = s. 4 consecutive s per
        // reg group -> packed stores along V^T rows.
#pragma unroll
        for (int ni = 0; ni < 2; ++ni) {
            int n = nb + ni * 32 + l31;
            int vrow = n - 2 * DM;                 // h*64+d, 0..1023
            float bvs = bias[n];
            bf16* row = Vt + (size_t)vrow * SEQ;
#pragma unroll
            for (int mi = 0; mi < 2; ++mi) {
#pragma unroll
                for (int rg = 0; rg < 4; ++rg) {
                    int s4 = m0 + wm + mi * 32 + rg * 8 + lhalf * 4;
                    bf16x4 o = {(bf16)(acc[mi][ni][rg * 4 + 0] + bvs),
                                (bf16)(acc[mi][ni][rg * 4 + 1] + bvs),
                                (bf16)(acc[mi][ni][rg * 4 + 2] + bvs),
                                (bf16)(acc[mi][ni][rg * 4 + 3] + bvs)};
                    *(bf16x4*)(row + s4) = o;
                }
            }
        }
    }
}

// ---- out-projection GEMM (swapped, row-major fp32 out), BM=64, BK=64.
// 512 blocks = 2/CU (r8 showed BM=128 @1/CU regresses: barrier drain naked).
template <int BM, typename TOUT>
__global__ __launch_bounds__(256, 4) void gemm_sw_kernel(
    const bf16* __restrict__ A, const bf16* __restrict__ B,
    const float* __restrict__ bias, TOUT* __restrict__ C,
    int M, int N, int K)
{
    constexpr int MI = BM / 32;
    __shared__ bf16 As[BM * 64];
    __shared__ bf16 Bs[128 * 64];

    const int tid  = threadIdx.x;
    const int wave = tid >> 6;
    const int lane = tid & 63;
    const int l15  = lane & 15;
    const int quad = lane >> 4;
    const int m0 = blockIdx.x * BM;
    const int n0 = blockIdx.y * 128;
    const int wm = (wave & 1) * (BM / 2);
    const int wn = (wave >> 1) * 64;

    const int lr = lane >> 3;
    const int gc = ((lane & 7) - lr) & 7;

    const bf16* aptr[MI]; bf16* alds[MI];
    const bf16* bptr[4];  bf16* blds[4];
#pragma unroll
    for (int i = 0; i < MI; ++i) {
        int ci = wave + 4 * i;
        aptr[i] = A + (size_t)(m0 + ci * 8 + lr) * K + gc * 8;
        alds[i] = As + ci * 512;
    }
#pragma unroll
    for (int j = 0; j < 4; ++j) {
        int cj = wave + 4 * j;
        bptr[j] = B + (size_t)(n0 + cj * 8 + lr) * K + gc * 8;
        blds[j] = Bs + cj * 512;
    }

    floatx4 acc[MI][4] = {};
    const int sw0 = (quad + (l15 & 7)) & 7;

    for (int k0 = 0; k0 < K; k0 += 64) {
        __syncthreads();
#pragma unroll
        for (int i = 0; i < MI; ++i) async_ld16(aptr[i] + k0, alds[i]);
#pragma unroll
        for (int j = 0; j < 4; ++j) async_ld16(bptr[j] + k0, blds[j]);
        __syncthreads();
#pragma unroll
        for (int h = 0; h < 2; ++h) {
            const int so = ((sw0 + 4 * h) & 7) * 8;
            bf16x8 af[MI], bfr[4];
#pragma unroll
            for (int i = 0; i < MI; ++i)
                af[i] = load8(As + (wm + i * 16 + l15) * 64 + so);
#pragma unroll
            for (int j = 0; j < 4; ++j)
                bfr[j] = load8(Bs + (wn + j * 16 + l15) * 64 + so);
#pragma unroll
            for (int i = 0; i < MI; ++i)
#pragma unroll
                for (int j = 0; j < 4; ++j)
                    acc[i][j] = mfma32(bfr[j], af[i], acc[i][j]);
        }
    }

#pragma unroll
    for (int i = 0; i < MI; ++i) {
        int xm = m0 + wm + i * 16 + l15;
#pragma unroll
        for (int j = 0; j < 4; ++j) {
            int cn = n0 + wn + j * 16 + quad * 4;
            float4 bv = *(const float4*)(bias + cn);
            float v0 = acc[i][j][0] + bv.x;
            float v1 = acc[i][j][1] + bv.y;
            float v2 = acc[i][j][2] + bv.z;
            float v3 = acc[i][j][3] + bv.w;
            if constexpr (sizeof(TOUT) == 2) {
                bf16x4 o = {(bf16)v0, (bf16)v1, (bf16)v2, (bf16)v3};
                *(bf16x4*)((bf16*)C + (size_t)xm * N + cn) = o;
            } else {
                float4 o = {v0, v1, v2, v3};
                *(float4*)((float*)C + (size_t)xm * N + cn) = o;
            }
        }
    }
}

// ---- sliding-window attention, head-major inputs, zero barriers (r7 form).
// Qh,Kh: [h][s][64]; Vt: [h*64+d][SEQ] (base has 64-elem guard each side).
__global__ __launch_bounds__(256, 4) void swattn_kernel(
    const bf16* __restrict__ Qh, const bf16* __restrict__ Kh,
    const bf16* __restrict__ Vt, bf16* __restrict__ ctx)
{
    __shared__ bf16 Pc[4][16][40];
    __shared__ float lred[4][16];

    const int tid  = threadIdx.x;
    const int wave = tid >> 6;
    const int lane = tid & 63;
    const int l15  = lane & 15;
    const int quad = lane >> 4;
    const int q0   = blockIdx.x * 64;
    const int h    = blockIdx.y;
    const int hoff = h * HD;

    const bf16* qhead = Qh + (size_t)h * SEQ * 64;
    const bf16* khead = Kh + (size_t)h * SEQ * 64;
    const bf16* vhead = Vt + (size_t)hoff * SEQ;

    const int qrow = q0 + wave * 16 + l15;
    bf16x8 aq0 = load8(qhead + (size_t)qrow * 64 + quad * 8);
    bf16x8 aq1 = load8(qhead + (size_t)qrow * 64 + quad * 8 + 32);

    const int ws = q0 - 64 + wave * 16;   // wave window start (global key)
    floatx4 s[9];
#pragma unroll
    for (int st = 0; st < 9; ++st) {
        int kr = ws + st * 16 + l15;
        int kc2 = kr < 0 ? 0 : (kr > SEQ - 1 ? SEQ - 1 : kr);
        const bf16* kp = khead + (size_t)kc2 * 64 + quad * 8;
        bf16x8 b0 = load8(kp), b1 = load8(kp + 32);
        floatx4 acc = {};
        acc = mfma32(aq0, b0, acc);
        acc = mfma32(aq1, b1, acc);
        s[st] = acc;
    }

    // mask + one-shot softmax in log2 space (v_exp_f32 is native exp2):
    // scale = 0.125 * log2(e). row = quad*4+r, key = ws + 16*st + l15
    const float SC2 = 0.18033688011112042f;
#pragma unroll
    for (int r = 0; r < 4; ++r) {
        int row = quad * 4 + r;
        float mx = -INFINITY;
#pragma unroll
        for (int st = 0; st < 9; ++st) {
            int j = st * 16 + l15;
            int gk = ws + j;
            bool ok = (j >= row) && (j <= 128 + row) && (gk >= 0) && (gk < SEQ);
            float v = ok ? s[st][r] * SC2 : -1e30f;
            s[st][r] = v;
            mx = fmaxf(mx, v);
        }
        mx = fmaxf(mx, __shfl_xor(mx, 1));
        mx = fmaxf(mx, __shfl_xor(mx, 2));
        mx = fmaxf(mx, __shfl_xor(mx, 4));
        mx = fmaxf(mx, __shfl_xor(mx, 8));
        float sum = 0.f;
#pragma unroll
        for (int st = 0; st < 9; ++st) {
            float p = __builtin_amdgcn_exp2f(s[st][r] - mx);
            s[st][r] = p;
            sum += p;
        }
        sum += __shfl_xor(sum, 1);
        sum += __shfl_xor(sum, 2);
        sum += __shfl_xor(sum, 4);
        sum += __shfl_xor(sum, 8);
        lred[wave][row] = sum;   // wave-private slot, wave-ordered LDS
    }

    // PV, operand-swapped: a = V^T frag straight from global, b = P frag.
    floatx4 ot[4] = {};
#pragma unroll
    for (int kc = 0; kc < 5; ++kc) {
#pragma unroll
        for (int r = 0; r < 4; ++r) {
            int row = quad * 4 + r;
            Pc[wave][row][l15] = (bf16)s[2 * kc][r];
            Pc[wave][row][16 + l15] = (kc < 4) ? (bf16)s[2 * kc + 1][r] : (bf16)0.f;
        }
        bf16x8 pb = load8(&Pc[wave][l15][quad * 8]);
#pragma unroll
        for (int dt = 0; dt < 4; ++dt) {
            const bf16* vp = vhead + (ptrdiff_t)(dt * 16 + l15) * SEQ
                                   + (ptrdiff_t)(ws + kc * 32 + quad * 8);
            ot[dt] = mfma32(load8(vp), pb, ot[dt]);
        }
    }

    float linv = 1.0f / lred[wave][l15];
#pragma unroll
    for (int dt = 0; dt < 4; ++dt) {
        bf16x4 o4;
#pragma unroll
        for (int r = 0; r < 4; ++r) o4[r] = (bf16)(ot[dt][r] * linv);
        *(bf16x4*)(ctx + (size_t)qrow * DM + hoff + dt * 16 + quad * 4) = o4;
    }
}

extern "C" void kernel_launch(void* const* d_in, const int* in_sizes, int n_in,
                              void* d_out, int out_size, void* d_ws, size_t ws_size,
                              hipStream_t stream) {
    const float* x  = (const float*)d_in[0];
    const float* Wq = (const float*)d_in[1];
    const float* bq = (const float*)d_in[2];
    const float* Wk = (const float*)d_in[3];
    const float* bk = (const float*)d_in[4];
    const float* Wv = (const float*)d_in[5];
    const float* bv = (const float*)d_in[6];
    const float* Wo = (const float*)d_in[7];
    const float* bo = (const float*)d_in[8];
    float* out = (float*)d_out;

    const size_t XN = (size_t)SEQ * DM;
    const size_t WN = (size_t)DM * DM;

    bf16* xb    = (bf16*)d_ws;            // XN ; reused as ctx after QKV GEMM
    bf16* Wcat  = xb + XN;                // 3*WN
    bf16* Wob   = Wcat + 3 * WN;          // WN
    bf16* Qh    = Wob + WN;               // XN
    bf16* Kh    = Qh + XN;                // XN
    bf16* VtRaw = Kh + XN;                // XN + 2*GUARD + 128
    bf16* Vtb   = VtRaw + GUARD;
    float* bcat = (float*)(VtRaw + XN + 2 * GUARD + 128);  // 3072 fp32
    bf16* ctx   = xb;                     // alias: xb dead after QKV GEMM

    prep_kernel<<<4097, 256, 0, stream>>>(x, Wq, Wk, Wv, Wo, bq, bk, bv,
                                          xb, Wcat, Wob, bcat);

    gemm_qkv_kernel<<<dim3(SEQ / 128, 24), 256, 0, stream>>>(
        xb, Wcat, bcat, Qh, Kh, Vtb);

    swattn_kernel<<<dim3(SEQ / 64, NH), 256, 0, stream>>>(Qh, Kh, Vtb, ctx);

    gemm_sw_kernel<64, float><<<dim3(SEQ / 64, DM / 128), 256, 0, stream>>>(
        ctx, Wob, bo, out, SEQ, DM, DM);
}

// Round 12
// 162.456 us; speedup vs baseline: 1.0429x; 1.0429x over previous
//
#include <hip/hip_runtime.h>
#include <type_traits>

typedef __bf16 bf16;
typedef __bf16 bf16x8 __attribute__((ext_vector_type(8)));
typedef __bf16 bf16x4 __attribute__((ext_vector_type(4)));
typedef float floatx4 __attribute__((ext_vector_type(4)));

#define SEQ 4096
#define DM 1024
#define NH 16
#define HD 64
#define GUARD 64

__device__ __forceinline__ floatx4 mfma32(bf16x8 a, bf16x8 b, floatx4 c) {
    return __builtin_amdgcn_mfma_f32_16x16x32_bf16(a, b, c, 0, 0, 0);
}

__device__ __forceinline__ bf16x8 load8(const bf16* p) {
    return *(const bf16x8*)p;
}

__device__ __forceinline__ void async_ld16(const bf16* g, bf16* l) {
    __builtin_amdgcn_global_load_lds(
        (const __attribute__((address_space(1))) unsigned int*)g,
        (__attribute__((address_space(3))) unsigned int*)l,
        16, 0, 0);
}

// fused prep: cast x, Wq,Wk,Wv,Wo to bf16; concat biases to fp32 bcat.
__global__ __launch_bounds__(256) void prep_kernel(
    const float* __restrict__ x,  const float* __restrict__ Wq,
    const float* __restrict__ Wk, const float* __restrict__ Wv,
    const float* __restrict__ Wo, const float* __restrict__ bq,
    const float* __restrict__ bk, const float* __restrict__ bv,
    bf16* __restrict__ xb, bf16* __restrict__ Wcat,
    bf16* __restrict__ Wob, float* __restrict__ bcat)
{
    const int WN8 = 131072;           // (1024*1024)/8
    const int XN8 = 524288;           // (4096*1024)/8
    int b = blockIdx.x;
    if (b == 4096) {
        for (int k = threadIdx.x; k < 3 * DM; k += 256)
            bcat[k] = k < DM ? bq[k] : (k < 2 * DM ? bk[k - DM] : bv[k - 2 * DM]);
        return;
    }
    int c = b * 256 + threadIdx.x;
    const float* src; bf16* dst;
    if (c < XN8)              { src = x;  dst = xb; }
    else if (c < XN8 + WN8)   { src = Wq; dst = Wcat;                 c -= XN8; }
    else if (c < XN8 + 2*WN8) { src = Wk; dst = Wcat + (size_t)DM*DM;     c -= XN8 + WN8; }
    else if (c < XN8 + 3*WN8) { src = Wv; dst = Wcat + (size_t)2*DM*DM;   c -= XN8 + 2*WN8; }
    else                      { src = Wo; dst = Wob;                  c -= XN8 + 3*WN8; }
    float4 a = ((const float4*)src)[2 * c], d2 = ((const float4*)src)[2 * c + 1];
    bf16x8 o;
    o[0] = (bf16)a.x;  o[1] = (bf16)a.y;  o[2] = (bf16)a.z;  o[3] = (bf16)a.w;
    o[4] = (bf16)d2.x; o[5] = (bf16)d2.y; o[6] = (bf16)d2.z; o[7] = (bf16)d2.w;
    *(bf16x8*)(dst + 8 * (size_t)c) = o;
}

// ---- QKV projection GEMM: [4096,1024] @ [3072,1024]^T, head-major outputs.
// BM=128, BN=128, BK=64, XOR-swizzled LDS (0 bank conflicts, verified r6).
// 16x16x32 MFMA with 16 independent accumulators (r11 showed 32x32x16 with
// only 4 acc chains regresses: less ILP + swizzle phase collisions).
// launch_bounds(256,3): 3 blocks/CU resident (verified r7: 171->161).
__global__ __launch_bounds__(256, 3) void gemm_qkv_kernel(
    const bf16* __restrict__ A,      // xb [4096][1024]
    const bf16* __restrict__ B,      // Wcat [3072][1024]
    const float* __restrict__ bias,  // bcat [3072]
    bf16* __restrict__ Qh, bf16* __restrict__ Kh, bf16* __restrict__ Vt)
{
    constexpr int K = DM;
    __shared__ bf16 As[128 * 64];
    __shared__ bf16 Bs[128 * 64];

    const int tid  = threadIdx.x;
    const int wave = tid >> 6;
    const int lane = tid & 63;
    const int l15  = lane & 15;
    const int quad = lane >> 4;
    const int m0 = blockIdx.x * 128;
    const int n0 = blockIdx.y * 128;
    const int wm = (wave & 1) * 64;
    const int wn = (wave >> 1) * 64;

    const int lr = lane >> 3;
    const int gc = ((lane & 7) - lr) & 7;

    const bf16* aptr[4]; bf16* alds[4];
    const bf16* bptr[4]; bf16* blds[4];
#pragma unroll
    for (int i = 0; i < 4; ++i) {
        int ci = wave + 4 * i;
        aptr[i] = A + (size_t)(m0 + ci * 8 + lr) * K + gc * 8;
        alds[i] = As + ci * 512;
        bptr[i] = B + (size_t)(n0 + ci * 8 + lr) * K + gc * 8;
        blds[i] = Bs + ci * 512;
    }

    floatx4 acc[4][4] = {};
    const int sw0 = (quad + (l15 & 7)) & 7;
    const bool qk = (n0 < 2 * DM);

    auto kloop = [&](auto swtag) {
        constexpr bool SW = decltype(swtag)::value;
        for (int k0 = 0; k0 < K; k0 += 64) {
            __syncthreads();
#pragma unroll
            for (int i = 0; i < 4; ++i) async_ld16(aptr[i] + k0, alds[i]);
#pragma unroll
            for (int i = 0; i < 4; ++i) async_ld16(bptr[i] + k0, blds[i]);
            __syncthreads();
#pragma unroll
            for (int h = 0; h < 2; ++h) {
                const int so = ((sw0 + 4 * h) & 7) * 8;
                bf16x8 af[4], bfr[4];
#pragma unroll
                for (int i = 0; i < 4; ++i)
                    af[i] = load8(As + (wm + i * 16 + l15) * 64 + so);
#pragma unroll
                for (int j = 0; j < 4; ++j)
                    bfr[j] = load8(Bs + (wn + j * 16 + l15) * 64 + so);
#pragma unroll
                for (int i = 0; i < 4; ++i)
#pragma unroll
                    for (int j = 0; j < 4; ++j)
                        acc[i][j] = SW ? mfma32(bfr[j], af[i], acc[i][j])
                                       : mfma32(af[i], bfr[j], acc[i][j]);
            }
        }
    };
    if (qk) kloop(std::true_type{}); else kloop(std::false_type{});

    const int nb = n0 + wn;   // multiple of 64
    if (qk) {
        bf16* dst = (nb < DM) ? Qh : Kh;
        const int hh = ((nb < DM) ? nb : nb - DM) >> 6;
#pragma unroll
        for (int i = 0; i < 4; ++i) {
            int s = m0 + wm + i * 16 + l15;
            bf16* row = dst + ((size_t)hh * SEQ + s) * 64;
#pragma unroll
            for (int j = 0; j < 4; ++j) {
                int d4 = j * 16 + quad * 4;
                float4 bv = *(const float4*)(bias + nb + d4);
                bf16x4 o = {(bf16)(acc[i][j][0] + bv.x), (bf16)(acc[i][j][1] + bv.y),
                            (bf16)(acc[i][j][2] + bv.z), (bf16)(acc[i][j][3] + bv.w)};
                *(bf16x4*)(row + d4) = o;
            }
        }
    } else {
#pragma unroll
        for (int j = 0; j < 4; ++j) {
            int vrow = (nb - 2 * DM) + j * 16 + l15;     // h*64+d, 0..1023
            float bvs = bias[nb + j * 16 + l15];
            bf16* row = Vt + (size_t)vrow * SEQ;
#pragma unroll
            for (int i = 0; i < 4; ++i) {
                int s4 = m0 + wm + i * 16 + quad * 4;
                bf16x4 o = {(bf16)(acc[i][j][0] + bvs), (bf16)(acc[i][j][1] + bvs),
                            (bf16)(acc[i][j][2] + bvs), (bf16)(acc[i][j][3] + bvs)};
                *(bf16x4*)(row + s4) = o;
            }
        }
    }
}

// ---- out-projection GEMM (swapped, row-major fp32 out), BM=64, BK=64.
// 512 blocks = 2/CU (r8 showed BM=128 @1/CU regresses: barrier drain naked).
template <int BM, typename TOUT>
__global__ __launch_bounds__(256, 4) void gemm_sw_kernel(
    const bf16* __restrict__ A, const bf16* __restrict__ B,
    const float* __restrict__ bias, TOUT* __restrict__ C,
    int M, int N, int K)
{
    constexpr int MI = BM / 32;
    __shared__ bf16 As[BM * 64];
    __shared__ bf16 Bs[128 * 64];

    const int tid  = threadIdx.x;
    const int wave = tid >> 6;
    const int lane = tid & 63;
    const int l15  = lane & 15;
    const int quad = lane >> 4;
    const int m0 = blockIdx.x * BM;
    const int n0 = blockIdx.y * 128;
    const int wm = (wave & 1) * (BM / 2);
    const int wn = (wave >> 1) * 64;

    const int lr = lane >> 3;
    const int gc = ((lane & 7) - lr) & 7;

    const bf16* aptr[MI]; bf16* alds[MI];
    const bf16* bptr[4];  bf16* blds[4];
#pragma unroll
    for (int i = 0; i < MI; ++i) {
        int ci = wave + 4 * i;
        aptr[i] = A + (size_t)(m0 + ci * 8 + lr) * K + gc * 8;
        alds[i] = As + ci * 512;
    }
#pragma unroll
    for (int j = 0; j < 4; ++j) {
        int cj = wave + 4 * j;
        bptr[j] = B + (size_t)(n0 + cj * 8 + lr) * K + gc * 8;
        blds[j] = Bs + cj * 512;
    }

    floatx4 acc[MI][4] = {};
    const int sw0 = (quad + (l15 & 7)) & 7;

    for (int k0 = 0; k0 < K; k0 += 64) {
        __syncthreads();
#pragma unroll
        for (int i = 0; i < MI; ++i) async_ld16(aptr[i] + k0, alds[i]);
#pragma unroll
        for (int j = 0; j < 4; ++j) async_ld16(bptr[j] + k0, blds[j]);
        __syncthreads();
#pragma unroll
        for (int h = 0; h < 2; ++h) {
            const int so = ((sw0 + 4 * h) & 7) * 8;
            bf16x8 af[MI], bfr[4];
#pragma unroll
            for (int i = 0; i < MI; ++i)
                af[i] = load8(As + (wm + i * 16 + l15) * 64 + so);
#pragma unroll
            for (int j = 0; j < 4; ++j)
                bfr[j] = load8(Bs + (wn + j * 16 + l15) * 64 + so);
#pragma unroll
            for (int i = 0; i < MI; ++i)
#pragma unroll
                for (int j = 0; j < 4; ++j)
                    acc[i][j] = mfma32(bfr[j], af[i], acc[i][j]);
        }
    }

#pragma unroll
    for (int i = 0; i < MI; ++i) {
        int xm = m0 + wm + i * 16 + l15;
#pragma unroll
        for (int j = 0; j < 4; ++j) {
            int cn = n0 + wn + j * 16 + quad * 4;
            float4 bv = *(const float4*)(bias + cn);
            float v0 = acc[i][j][0] + bv.x;
            float v1 = acc[i][j][1] + bv.y;
            float v2 = acc[i][j][2] + bv.z;
            float v3 = acc[i][j][3] + bv.w;
            if constexpr (sizeof(TOUT) == 2) {
                bf16x4 o = {(bf16)v0, (bf16)v1, (bf16)v2, (bf16)v3};
                *(bf16x4*)((bf16*)C + (size_t)xm * N + cn) = o;
            } else {
                float4 o = {v0, v1, v2, v3};
                *(float4*)((float*)C + (size_t)xm * N + cn) = o;
            }
        }
    }
}

// ---- sliding-window attention, head-major inputs, zero barriers (r7 form).
// Qh,Kh: [h][s][64]; Vt: [h*64+d][SEQ] (base has 64-elem guard each side).
__global__ __launch_bounds__(256, 4) void swattn_kernel(
    const bf16* __restrict__ Qh, const bf16* __restrict__ Kh,
    const bf16* __restrict__ Vt, bf16* __restrict__ ctx)
{
    __shared__ bf16 Pc[4][16][40];
    __shared__ float lred[4][16];

    const int tid  = threadIdx.x;
    const int wave = tid >> 6;
    const int lane = tid & 63;
    const int l15  = lane & 15;
    const int quad = lane >> 4;
    const int q0   = blockIdx.x * 64;
    const int h    = blockIdx.y;
    const int hoff = h * HD;

    const bf16* qhead = Qh + (size_t)h * SEQ * 64;
    const bf16* khead = Kh + (size_t)h * SEQ * 64;
    const bf16* vhead = Vt + (size_t)hoff * SEQ;

    const int qrow = q0 + wave * 16 + l15;
    bf16x8 aq0 = load8(qhead + (size_t)qrow * 64 + quad * 8);
    bf16x8 aq1 = load8(qhead + (size_t)qrow * 64 + quad * 8 + 32);

    const int ws = q0 - 64 + wave * 16;   // wave window start (global key)
    floatx4 s[9];
#pragma unroll
    for (int st = 0; st < 9; ++st) {
        int kr = ws + st * 16 + l15;
        int kc2 = kr < 0 ? 0 : (kr > SEQ - 1 ? SEQ - 1 : kr);
        const bf16* kp = khead + (size_t)kc2 * 64 + quad * 8;
        bf16x8 b0 = load8(kp), b1 = load8(kp + 32);
        floatx4 acc = {};
        acc = mfma32(aq0, b0, acc);
        acc = mfma32(aq1, b1, acc);
        s[st] = acc;
    }

    // mask + one-shot softmax in log2 space (v_exp_f32 is native exp2):
    // scale = 0.125 * log2(e). row = quad*4+r, key = ws + 16*st + l15
    const float SC2 = 0.18033688011112042f;
#pragma unroll
    for (int r = 0; r < 4; ++r) {
        int row = quad * 4 + r;
        float mx = -INFINITY;
#pragma unroll
        for (int st = 0; st < 9; ++st) {
            int j = st * 16 + l15;
            int gk = ws + j;
            bool ok = (j >= row) && (j <= 128 + row) && (gk >= 0) && (gk < SEQ);
            float v = ok ? s[st][r] * SC2 : -1e30f;
            s[st][r] = v;
            mx = fmaxf(mx, v);
        }
        mx = fmaxf(mx, __shfl_xor(mx, 1));
        mx = fmaxf(mx, __shfl_xor(mx, 2));
        mx = fmaxf(mx, __shfl_xor(mx, 4));
        mx = fmaxf(mx, __shfl_xor(mx, 8));
        float sum = 0.f;
#pragma unroll
        for (int st = 0; st < 9; ++st) {
            float p = __builtin_amdgcn_exp2f(s[st][r] - mx);
            s[st][r] = p;
            sum += p;
        }
        sum += __shfl_xor(sum, 1);
        sum += __shfl_xor(sum, 2);
        sum += __shfl_xor(sum, 4);
        sum += __shfl_xor(sum, 8);
        lred[wave][row] = sum;   // wave-private slot, wave-ordered LDS
    }

    // PV, operand-swapped: a = V^T frag straight from global, b = P frag.
    floatx4 ot[4] = {};
#pragma unroll
    for (int kc = 0; kc < 5; ++kc) {
#pragma unroll
        for (int r = 0; r < 4; ++r) {
            int row = quad * 4 + r;
            Pc[wave][row][l15] = (bf16)s[2 * kc][r];
            Pc[wave][row][16 + l15] = (kc < 4) ? (bf16)s[2 * kc + 1][r] : (bf16)0.f;
        }
        bf16x8 pb = load8(&Pc[wave][l15][quad * 8]);
#pragma unroll
        for (int dt = 0; dt < 4; ++dt) {
            const bf16* vp = vhead + (ptrdiff_t)(dt * 16 + l15) * SEQ
                                   + (ptrdiff_t)(ws + kc * 32 + quad * 8);
            ot[dt] = mfma32(load8(vp), pb, ot[dt]);
        }
    }

    float linv = 1.0f / lred[wave][l15];
#pragma unroll
    for (int dt = 0; dt < 4; ++dt) {
        bf16x4 o4;
#pragma unroll
        for (int r = 0; r < 4; ++r) o4[r] = (bf16)(ot[dt][r] * linv);
        *(bf16x4*)(ctx + (size_t)qrow * DM + hoff + dt * 16 + quad * 4) = o4;
    }
}

extern "C" void kernel_launch(void* const* d_in, const int* in_sizes, int n_in,
                              void* d_out, int out_size, void* d_ws, size_t ws_size,
                              hipStream_t stream) {
    const float* x  = (const float*)d_in[0];
    const float* Wq = (const float*)d_in[1];
    const float* bq = (const float*)d_in[2];
    const float* Wk = (const float*)d_in[3];
    const float* bk = (const float*)d_in[4];
    const float* Wv = (const float*)d_in[5];
    const float* bv = (const float*)d_in[6];
    const float* Wo = (const float*)d_in[7];
    const float* bo = (const float*)d_in[8];
    float* out = (float*)d_out;

    const size_t XN = (size_t)SEQ * DM;
    const size_t WN = (size_t)DM * DM;

    bf16* xb    = (bf16*)d_ws;            // XN ; reused as ctx after QKV GEMM
    bf16* Wcat  = xb + XN;                // 3*WN
    bf16* Wob   = Wcat + 3 * WN;          // WN
    bf16* Qh    = Wob + WN;               // XN
    bf16* Kh    = Qh + XN;                // XN
    bf16* VtRaw = Kh + XN;                // XN + 2*GUARD + 128
    bf16* Vtb   = VtRaw + GUARD;
    float* bcat = (float*)(VtRaw + XN + 2 * GUARD + 128);  // 3072 fp32
    bf16* ctx   = xb;                     // alias: xb dead after QKV GEMM

    prep_kernel<<<4097, 256, 0, stream>>>(x, Wq, Wk, Wv, Wo, bq, bk, bv,
                                          xb, Wcat, Wob, bcat);

    gemm_qkv_kernel<<<dim3(SEQ / 128, 24), 256, 0, stream>>>(
        xb, Wcat, bcat, Qh, Kh, Vtb);

    swattn_kernel<<<dim3(SEQ / 64, NH), 256, 0, stream>>>(Qh, Kh, Vtb, ctx);

    gemm_sw_kernel<64, float><<<dim3(SEQ / 64, DM / 128), 256, 0, stream>>>(
        ctx, Wob, bo, out, SEQ, DM, DM);
}